// Round 7
// baseline (328.258 us; speedup 1.0000x reference)
//
#include <hip/hip_runtime.h>
#include <stdint.h>

// _TransformerBlockQuantum on MI355X (gfx950).
// cast->bf16 | fused QKV GEMM (+V-transpose epilogue, XCD swizzle) | flash attn
// (barrier-free: direct L2 K/V fragment reads, in-block kv-split 2x4 waves,
// 32x32 MFMA, in-register P via permlane32_swap, log2 softmax, defer-max, LDS merge)
// | Wo GEMM | fused tail.

typedef unsigned short u16;
typedef unsigned int   u32;
typedef __bf16 bf16x8 __attribute__((ext_vector_type(8)));
typedef u16    u16x8  __attribute__((ext_vector_type(8)));
typedef u16    u16x4  __attribute__((ext_vector_type(4)));
typedef float  f32x4  __attribute__((ext_vector_type(4)));
typedef float  f32x16 __attribute__((ext_vector_type(16)));

#define DEV static __device__ __forceinline__

DEV u16 f2b(float f){ u32 u = __float_as_uint(f); return (u16)((u + 0x7fffu + ((u>>16)&1u)) >> 16); }
DEV u16 b2u(__bf16 h){ union{__bf16 b; u16 u;} c; c.b = h; return c.u; }
DEV float exp2fast(float x){ return __builtin_amdgcn_exp2f(x); }  // v_exp_f32 (2^x)

// permlane32_swap(a,b): out0 = (lane<32) ? a(own) : b(partner); out1 = (lane<32) ? a(partner) : b(own)
DEV void plswap(u32 a, u32 b, u32& o0, u32& o1, int hi){
#if __has_builtin(__builtin_amdgcn_permlane32_swap)
  auto s = __builtin_amdgcn_permlane32_swap(a, b, false, false);
  o0 = s[0]; o1 = s[1];
#else
  u32 xa = __shfl_xor(a, 32), xb = __shfl_xor(b, 32);
  o0 = hi ? xb : a;
  o1 = hi ? b  : xa;
#endif
}

#define MFMA16(a,b,c) __builtin_amdgcn_mfma_f32_16x16x32_bf16((a),(b),(c),0,0,0)
#define MFMA32(a,b,c) __builtin_amdgcn_mfma_f32_32x32x16_bf16((a),(b),(c),0,0,0)
#define GLD16(gp,lp) __builtin_amdgcn_global_load_lds( \
    (const __attribute__((address_space(1))) u32*)(const void*)(gp), \
    (__attribute__((address_space(3))) u32*)(void*)(lp), 16, 0, 0)

// ---------------- cast f32 -> bf16, 8 elems/thread ----------------
__global__ __launch_bounds__(256) void k_cast(const float* __restrict__ src, u16* __restrict__ dst){
  const int i = blockIdx.x*256 + threadIdx.x;
  const f32x4* s = (const f32x4*)src + (size_t)i*2;
  f32x4 a = s[0], b = s[1];
  u16x8 o;
  o[0]=f2b(a.x); o[1]=f2b(a.y); o[2]=f2b(a.z); o[3]=f2b(a.w);
  o[4]=f2b(b.x); o[5]=f2b(b.y); o[6]=f2b(b.z); o[7]=f2b(b.w);
  ((u16x8*)dst)[i] = o;
}

// all 4 weight matrices in one launch
__global__ __launch_bounds__(256) void k_cast_w(
    const float* __restrict__ Wq, const float* __restrict__ Wk,
    const float* __restrict__ Wv, const float* __restrict__ Wo,
    u16* __restrict__ wb, u16* __restrict__ wob){
  const int r = blockIdx.x >> 9, bi = blockIdx.x & 511;
  const float* src = (r==0)?Wq:((r==1)?Wk:((r==2)?Wv:Wo));
  u16* dst = (r<3) ? (wb + (size_t)r*1048576) : wob;
  const int i = bi*256 + threadIdx.x;
  const f32x4* s = (const f32x4*)src + (size_t)i*2;
  f32x4 a = s[0], b = s[1];
  u16x8 o;
  o[0]=f2b(a.x); o[1]=f2b(a.y); o[2]=f2b(a.z); o[3]=f2b(a.w);
  o[4]=f2b(b.x); o[5]=f2b(b.y); o[6]=f2b(b.z); o[7]=f2b(b.w);
  ((u16x8*)dst)[i] = o;
}

// ---------------- C = A * B^T  (A:[M,K] bf16, B:[N,K] bf16) ----------------
// XCD-aware bijective block swizzle (nwg % 8 == 0 for both launches).
// MODE 0: N=3072 fused QKV epilogue -> q(*0.125*log2e)/k row-major; V -> vt[(p*64+d)][s]
// MODE 1: f32 epilogue into Cf[M][N]
template<int MODE>
__global__ __launch_bounds__(256) void k_gemm_nt(
    const u16* __restrict__ A, const u16* __restrict__ B,
    float* __restrict__ Cf, u16* __restrict__ Qo, u16* __restrict__ Ko, u16* __restrict__ Vt,
    int K, int N)
{
  __shared__ __attribute__((aligned(16))) u16 As[128*64];
  __shared__ __attribute__((aligned(16))) u16 Bs[128*64];
  const int tid = threadIdx.x, lane = tid & 63, w = tid >> 6;
  const int wr = w >> 1, wc = w & 1;
  // XCD swizzle: chunk tile space per XCD
  const int nwg = gridDim.x * gridDim.y;
  int lin = blockIdx.y * gridDim.x + blockIdx.x;
  lin = (lin & 7) * (nwg >> 3) + (lin >> 3);
  const int n0 = (lin % gridDim.x) * 128;
  const int m0 = (lin / gridDim.x) * 128;
  const int l15 = lane & 15, lg = lane >> 4;
  f32x4 acc[4][4] = {};
  const int lr = lane >> 3, lc = (lane & 7)*8;
  const u16* ag = A + (size_t)(m0 + w*32 + lr)*K + lc;
  const u16* bg = B + (size_t)(n0 + w*32 + lr)*K + lc;
  u16* asl = &As[(w*32)*64];
  u16* bsl = &Bs[(w*32)*64];
  for (int k0 = 0; k0 < K; k0 += 64){
    __syncthreads();
    #pragma unroll
    for (int c = 0; c < 4; ++c){
      GLD16(ag + (size_t)(c*8)*K + k0, asl + c*512);
      GLD16(bg + (size_t)(c*8)*K + k0, bsl + c*512);
    }
    __syncthreads();
    #pragma unroll
    for (int kk = 0; kk < 2; ++kk){
      const int ko = kk*32 + lg*8;
      bf16x8 af[4], bf[4];
      #pragma unroll
      for (int t=0;t<4;++t) af[t] = *(const bf16x8*)&As[(wr*64 + t*16 + l15)*64 + ko];
      #pragma unroll
      for (int t=0;t<4;++t) bf[t] = *(const bf16x8*)&Bs[(wc*64 + t*16 + l15)*64 + ko];
      #pragma unroll
      for (int i=0;i<4;++i)
        #pragma unroll
        for (int j=0;j<4;++j)
          acc[i][j] = MFMA16(af[i], bf[j], acc[i][j]);
    }
  }
  const int col0 = n0 + wc*64 + l15;
  const int row0 = m0 + wr*64 + lg*4;
  if (MODE==0){
    const int which = n0 >> 10;   // uniform per block
    if (which == 2){
      #pragma unroll
      for (int i=0;i<4;++i){
        const int rr0 = row0 + i*16;
        const int bsel = rr0 >> 11, ss = rr0 & 2047;
        #pragma unroll
        for (int j=0;j<4;++j){
          const int d_loc = (col0 + j*16) & 1023;
          const int hh = d_loc >> 6, dd = d_loc & 63;
          u16x4 pk;
          #pragma unroll
          for (int r=0;r<4;++r) pk[r] = f2b(acc[i][j][r]);
          *(u16x4*)(Vt + ((size_t)((bsel*16 + hh)*64 + dd))*2048 + ss) = pk;
        }
      }
    } else {
      u16* dst = which ? Ko : Qo;
      const float scl = which ? 1.f : 0.125f*1.44269504f;  // fold log2(e) into q
      #pragma unroll
      for (int i=0;i<4;++i)
      #pragma unroll
      for (int j=0;j<4;++j){
        const int cc = (col0 + j*16) & 1023;
        #pragma unroll
        for (int r=0;r<4;++r)
          dst[(size_t)(row0 + i*16 + r)*1024 + cc] = f2b(acc[i][j][r]*scl);
      }
    }
  } else {
    #pragma unroll
    for (int i=0;i<4;++i)
    #pragma unroll
    for (int j=0;j<4;++j){
      const int cc = col0 + j*16;
      #pragma unroll
      for (int r=0;r<4;++r)
        Cf[(size_t)(row0 + i*16 + r)*N + cc] = acc[i][j][r];
    }
  }
}

// ---------------- flash attention, barrier-free direct-L2 reads ----------------
// grid 512, 512 threads: blockIdx = p*16 + qt; p=(b*16+h). 8 waves = 2 kv-groups x
// 4 q-subtiles of 32 rows. Group g covers kv in [g*1024,(g+1)*1024), 16 iters.
// K/V per head = 512KB -> L2-resident; 16 blocks share it. No LDS staging, no
// inner-loop barriers: each wave reads MFMA fragments straight from global and
// pipelines independently. q pre-scaled by 0.125*log2e; softmax in log2 domain.
// Lane: q/row = lane&31, hi = lane>>5.
// QK^T: S^T = MFMA32(Kfrag,Qfrag); PV: O^T = MFMA32(Vfrag,Pfrag); P built in-reg
// via cvt+permlane32_swap. End: group 1 posts bf16 O^T + (m,l) to LDS; group 0
// merges (flash-decode combine) and stores.
__global__ __launch_bounds__(512) void k_attn(
    const u16* __restrict__ q, const u16* __restrict__ k,
    const u16* __restrict__ vt, u16* __restrict__ o)
{
  __shared__ __attribute__((aligned(16))) char OB[16384];  // group-1 O^T bf16
  __shared__ __attribute__((aligned(16))) char MLB[1024];  // group-1 (m,l)
  const int tid = threadIdx.x, lane = tid & 63;
  const int wl = (tid >> 6) & 3, wg = tid >> 8;
  const int p = blockIdx.x >> 4, qt = blockIdx.x & 15;
  const int b = p >> 4, h = p & 15;
  const int l31 = lane & 31, hi = lane >> 5;
  const int qrow = b*2048 + qt*128 + wl*32 + l31;
  // Q fragments (B operand): col=q (lane l31), k-dim = d = kk*16 + hi*8 + j
  bf16x8 qa[4];
  #pragma unroll
  for (int kk=0;kk<4;++kk)
    qa[kk] = *(const bf16x8*)(q + (size_t)qrow*1024 + h*64 + kk*16 + hi*8);
  // K fragment base: row = b*2048 + wg*1024 + it*64 + t32*32 + l31, col = h*64 + kk*16 + hi*8
  const u16* kbase = k + (size_t)(b*2048 + wg*1024 + l31)*1024 + h*64 + hi*8;
  // V fragment base: row = p*64 + dt*32 + l31, col = wg*1024 + it*64 + op*16 + hi*8
  const u16* vbase = vt + (size_t)(p*64 + l31)*2048 + wg*1024 + hi*8;
  f32x16 oacc[2] = {};
  float mrow = -1e30f, lrow = 0.f;
  for (int it = 0; it < 16; ++it){
    const u16* kp = kbase + (size_t)(it*64)*1024;
    const u16* vp = vbase + it*64;
    // QK^T: two 32x32 tiles over kv, K=64 in 4 slices (fragments direct from L1/L2)
    f32x16 sacc[2] = {};
    #pragma unroll
    for (int t32=0;t32<2;++t32){
      bf16x8 kf[4];
      #pragma unroll
      for (int kk=0;kk<4;++kk)
        kf[kk] = *(const bf16x8*)(kp + (size_t)(t32*32)*1024 + kk*16);
      __builtin_amdgcn_s_setprio(1);
      #pragma unroll
      for (int kk=0;kk<4;++kk)
        sacc[t32] = MFMA32(kf[kk], qa[kk], sacc[t32]);
      __builtin_amdgcn_s_setprio(0);
    }
    // issue V loads early so they overlap the softmax VALU work
    bf16x8 vf[2][4];
    #pragma unroll
    for (int dt=0;dt<2;++dt)
      #pragma unroll
      for (int op=0;op<4;++op)
        vf[dt][op] = *(const bf16x8*)(vp + (size_t)(dt*32)*2048 + op*16);
    // online softmax (log2 domain), row q = l31; partner lane^32 holds the
    // complementary kv interleave of the same row.
    float mx = sacc[0][0];
    #pragma unroll
    for (int t32=0;t32<2;++t32)
      #pragma unroll
      for (int i=0;i<16;++i) mx = fmaxf(mx, sacc[t32][i]);
    mx = fmaxf(mx, __shfl_xor(mx, 32));
    if (!__all(mx <= mrow + 8.f)){       // defer-max
      const float mnew = fmaxf(mrow, mx);
      const float scl = exp2fast(mrow - mnew);
      mrow = mnew; lrow *= scl;
      #pragma unroll
      for (int dt=0;dt<2;++dt)
        #pragma unroll
        for (int i=0;i<16;++i) oacc[dt][i] *= scl;
    }
    float rsum = 0.f;
    #pragma unroll
    for (int t32=0;t32<2;++t32)
      #pragma unroll
      for (int i=0;i<16;++i){
        const float e = exp2fast(sacc[t32][i] - mrow);
        sacc[t32][i] = e; rsum += e;
      }
    rsum += __shfl_xor(rsum, 32);
    lrow += rsum;
    // pack P to bf16 pairs
    u32 pk[2][8];
    #pragma unroll
    for (int t32=0;t32<2;++t32)
      #pragma unroll
      for (int u=0;u<8;++u){
        const int idx = (u>>1)*4 + (u&1)*2;
        const u32 lo = b2u((__bf16)sacc[t32][idx]);
        const u32 hh = b2u((__bf16)sacc[t32][idx+1]);
        pk[t32][u] = lo | (hh << 16);
      }
    // PV B-frags via permlane32_swap
    bf16x8 pb[4];
    #pragma unroll
    for (int op=0;op<4;++op){
      const int t32 = op>>1, base = (op&1)*4;
      u32 w0,w1,w2,w3;
      plswap(pk[t32][base+0], pk[t32][base+2], w0, w2, hi);
      plswap(pk[t32][base+1], pk[t32][base+3], w1, w3, hi);
      union { u32 u[4]; bf16x8 v; } cc;
      cc.u[0]=w0; cc.u[1]=w1; cc.u[2]=w2; cc.u[3]=w3;
      pb[op] = cc.v;
    }
    // PV: O^T[d][q]
    __builtin_amdgcn_s_setprio(1);
    #pragma unroll
    for (int dt=0;dt<2;++dt)
      #pragma unroll
      for (int op=0;op<4;++op)
        oacc[dt] = MFMA32(vf[dt][op], pb[op], oacc[dt]);
    __builtin_amdgcn_s_setprio(0);
  }
  // ---- merge the two kv-halves via LDS ----
  __syncthreads();
  if (wg == 1){
    #pragma unroll
    for (int dt=0;dt<2;++dt)
    #pragma unroll
    for (int rg=0;rg<4;++rg)
    #pragma unroll
    for (int hf=0;hf<2;++hf){
      const int r0 = rg*4 + hf*2;
      const u32 lo = b2u((__bf16)oacc[dt][r0]);
      const u32 hh = b2u((__bf16)oacc[dt][r0+1]);
      const int j = dt*8 + rg*2 + hf;
      *(u32*)(OB + wl*4096 + j*256 + lane*4) = lo | (hh << 16);
    }
    if (hi == 0)
      *(float2*)(MLB + (wl*32 + l31)*8) = make_float2(mrow, lrow);
  }
  __syncthreads();
  if (wg == 0){
    const float2 ml1 = *(const float2*)(MLB + (wl*32 + l31)*8);
    const float m  = fmaxf(mrow, ml1.x);
    const float a0 = exp2fast(mrow - m), a1 = exp2fast(ml1.x - m);
    const float linv = 1.f / (lrow*a0 + ml1.y*a1);
    const float s0 = a0*linv, s1 = a1*linv;
    u16* orow = o + (size_t)qrow*1024 + h*64;
    #pragma unroll
    for (int dt=0;dt<2;++dt)
    #pragma unroll
    for (int rg=0;rg<4;++rg)
    #pragma unroll
    for (int hf=0;hf<2;++hf){
      const int r0 = rg*4 + hf*2;
      const int j = dt*8 + rg*2 + hf;
      const u32 pu = *(const u32*)(OB + wl*4096 + j*256 + lane*4);
      const float p0 = __uint_as_float(pu << 16);
      const float p1 = __uint_as_float(pu & 0xFFFF0000u);
      const float v0 = oacc[dt][r0]  *s0 + p0*s1;
      const float v1 = oacc[dt][r0+1]*s0 + p1*s1;
      *(u32*)(orow + dt*32 + rg*8 + hi*4 + hf*2) = (u32)b2u((__bf16)v0) | ((u32)b2u((__bf16)v1) << 16);
    }
  }
}

// ---------------- fused tail: LN1(x+attn) -> quantum FFN -> +res -> LN2 ----------------
__global__ __launch_bounds__(256) void k_tail(
    const float* __restrict__ x, const float* __restrict__ attn,
    const float* __restrict__ g1, const float* __restrict__ b1,
    const float* __restrict__ Win, const float* __restrict__ b_in,
    const float* __restrict__ Wout, const float* __restrict__ b_out,
    const float* __restrict__ ry,
    const float* __restrict__ g2, const float* __restrict__ b2,
    float* __restrict__ out)
{
  const int tid = threadIdx.x, lane = tid & 63, w = tid >> 6;
  const int t = blockIdx.x*4 + w;
  const size_t base = (size_t)t*1024;
  f32x4 yv[4];
  float s1 = 0.f, s2 = 0.f;
  #pragma unroll
  for (int c=0;c<4;++c){
    const int idx = c*256 + lane*4;
    f32x4 xv = *(const f32x4*)(x + base + idx);
    f32x4 av = *(const f32x4*)(attn + base + idx);
    f32x4 y = xv + av;
    yv[c] = y;
    s1 += y.x + y.y + y.z + y.w;
    s2 += y.x*y.x + y.y*y.y + y.z*y.z + y.w*y.w;
  }
  #pragma unroll
  for (int off=32; off; off>>=1){ s1 += __shfl_xor(s1, off); s2 += __shfl_xor(s2, off); }
  {
    const float mu = s1*(1.f/1024.f);
    const float rinv = rsqrtf(s2*(1.f/1024.f) - mu*mu + 1e-5f);
    #pragma unroll
    for (int c=0;c<4;++c){
      const int idx = c*256 + lane*4;
      f32x4 gv = *(const f32x4*)(g1 + idx);
      f32x4 bv = *(const f32x4*)(b1 + idx);
      f32x4 y = yv[c];
      y.x = (y.x-mu)*rinv*gv.x + bv.x;
      y.y = (y.y-mu)*rinv*gv.y + bv.y;
      y.z = (y.z-mu)*rinv*gv.z + bv.z;
      y.w = (y.w-mu)*rinv*gv.w + bv.w;
      yv[c] = y;
    }
  }
  float ang[8];
  #pragma unroll
  for (int qq=0; qq<8; ++qq){
    float acc = 0.f;
    #pragma unroll
    for (int c=0;c<4;++c){
      f32x4 wv = *(const f32x4*)(Win + qq*1024 + c*256 + lane*4);
      acc += wv.x*yv[c].x + wv.y*yv[c].y + wv.z*yv[c].z + wv.w*yv[c].w;
    }
    ang[qq] = acc;
  }
  #pragma unroll
  for (int off=32; off; off>>=1)
    #pragma unroll
    for (int qq=0; qq<8; ++qq) ang[qq] += __shfl_xor(ang[qq], off);
  #pragma unroll
  for (int qq=0; qq<8; ++qq) ang[qq] += b_in[qq];
  float vr[4], vi[4];
  #pragma unroll
  for (int r=0;r<4;++r){ vr[r]=0.f; vi[r]=0.f; }
  if (lane==0) vr[0] = 1.f;
  #pragma unroll
  for (int wi=0; wi<8; ++wi){       // RX(ang)
    float s, c; __sincosf(ang[wi]*0.5f, &s, &c);
    const int pbit = 7 - wi;
    if (pbit >= 6){
      const int rp = 1 << (pbit-6);
      #pragma unroll
      for (int r=0;r<4;++r) if (!(r & rp)){
        const int r2 = r | rp;
        float ar=vr[r], ai=vi[r], br=vr[r2], bi=vi[r2];
        vr[r]  = c*ar + s*bi;  vi[r]  = c*ai - s*br;
        vr[r2] = c*br + s*ai;  vi[r2] = c*bi - s*ar;
      }
    } else {
      const int msk = 1 << pbit;
      #pragma unroll
      for (int r=0;r<4;++r){
        float orr = __shfl_xor(vr[r], msk);
        float oii = __shfl_xor(vi[r], msk);
        float nr = c*vr[r] + s*oii;
        float ni = c*vi[r] - s*orr;
        vr[r]=nr; vi[r]=ni;
      }
    }
  }
  #pragma unroll
  for (int wi=0; wi<8; ++wi){       // RY(ry)
    float s, c; __sincosf(ry[wi]*0.5f, &s, &c);
    const int pbit = 7 - wi;
    if (pbit >= 6){
      const int rp = 1 << (pbit-6);
      #pragma unroll
      for (int r=0;r<4;++r) if (!(r & rp)){
        const int r2 = r | rp;
        float ar=vr[r], ai=vi[r], br=vr[r2], bi=vi[r2];
        vr[r]  = c*ar - s*br;  vi[r]  = c*ai - s*bi;
        vr[r2] = s*ar + c*br;  vi[r2] = s*ai + c*bi;
      }
    } else {
      const int msk = 1 << pbit;
      const float sg = (lane & msk) ? s : -s;
      #pragma unroll
      for (int r=0;r<4;++r){
        float orr = __shfl_xor(vr[r], msk);
        float oii = __shfl_xor(vi[r], msk);
        float nr = c*vr[r] + sg*orr;
        float ni = c*vi[r] + sg*oii;
        vr[r]=nr; vi[r]=ni;
      }
    }
  }
  { float tr=vr[2]; vr[2]=vr[3]; vr[3]=tr; float ti=vi[2]; vi[2]=vi[3]; vi[3]=ti; }
  vr[1]=__shfl_xor(vr[1],32); vi[1]=__shfl_xor(vi[1],32);
  vr[3]=__shfl_xor(vr[3],32); vi[3]=__shfl_xor(vi[3],32);
  #pragma unroll
  for (int cn=2; cn<7; ++cn){
    const int pc = 7-cn, pt = pc-1;
    const bool ctl = (lane >> pc) & 1;
    #pragma unroll
    for (int r=0;r<4;++r){
      float tr = __shfl_xor(vr[r], 1<<pt);
      float ti = __shfl_xor(vi[r], 1<<pt);
      if (ctl){ vr[r]=tr; vi[r]=ti; }
    }
  }
  float pr[4];
  #pragma unroll
  for (int r=0;r<4;++r) pr[r] = vr[r]*vr[r] + vi[r]*vi[r];
  float e[8];
  e[0] = (pr[0]+pr[1]) - (pr[2]+pr[3]);
  e[1] = (pr[0]+pr[2]) - (pr[1]+pr[3]);
  const float tot = pr[0]+pr[1]+pr[2]+pr[3];
  #pragma unroll
  for (int wi=2; wi<8; ++wi){
    const int pbit = 7-wi;
    e[wi] = ((lane >> pbit) & 1) ? -tot : tot;
  }
  #pragma unroll
  for (int off=1; off<64; off<<=1)
    #pragma unroll
    for (int i=0;i<8;++i) e[i] += __shfl_xor(e[i], off);
  float yy[4][4];
  s1 = 0.f; s2 = 0.f;
  #pragma unroll
  for (int c=0;c<4;++c){
    const float x1a[4] = {yv[c].x, yv[c].y, yv[c].z, yv[c].w};
    #pragma unroll
    for (int j=0;j<4;++j){
      const int d = c*256 + lane*4 + j;
      f32x4 w0 = *(const f32x4*)(Wout + (size_t)d*8);
      f32x4 w1 = *(const f32x4*)(Wout + (size_t)d*8 + 4);
      float acc = b_out[d];
      acc += w0.x*e[0] + w0.y*e[1] + w0.z*e[2] + w0.w*e[3];
      acc += w1.x*e[4] + w1.y*e[5] + w1.z*e[6] + w1.w*e[7];
      const float y = x1a[j] + fmaxf(acc, 0.f);
      yy[c][j] = y;
      s1 += y; s2 += y*y;
    }
  }
  #pragma unroll
  for (int off=32; off; off>>=1){ s1 += __shfl_xor(s1, off); s2 += __shfl_xor(s2, off); }
  const float mu = s1*(1.f/1024.f);
  const float rinv = rsqrtf(s2*(1.f/1024.f) - mu*mu + 1e-5f);
  #pragma unroll
  for (int c=0;c<4;++c){
    const int idx = c*256 + lane*4;
    f32x4 gv = *(const f32x4*)(g2 + idx);
    f32x4 bv = *(const f32x4*)(b2 + idx);
    f32x4 ov;
    ov.x = (yy[c][0]-mu)*rinv*gv.x + bv.x;
    ov.y = (yy[c][1]-mu)*rinv*gv.y + bv.y;
    ov.z = (yy[c][2]-mu)*rinv*gv.z + bv.z;
    ov.w = (yy[c][3]-mu)*rinv*gv.w + bv.w;
    *(f32x4*)(out + base + idx) = ov;
  }
}

extern "C" void kernel_launch(void* const* d_in, const int* in_sizes, int n_in,
                              void* d_out, int out_size, void* d_ws, size_t ws_size,
                              hipStream_t stream)
{
  const float* x    = (const float*)d_in[0];
  const float* Wq   = (const float*)d_in[1];
  const float* Wk   = (const float*)d_in[2];
  const float* Wv   = (const float*)d_in[3];
  const float* Wo   = (const float*)d_in[4];
  const float* g1   = (const float*)d_in[5];
  const float* b1   = (const float*)d_in[6];
  const float* g2   = (const float*)d_in[7];
  const float* b2   = (const float*)d_in[8];
  const float* Win  = (const float*)d_in[9];
  const float* b_in = (const float*)d_in[10];
  const float* Wout = (const float*)d_in[11];
  const float* b_out= (const float*)d_in[12];
  const float* ry   = (const float*)d_in[13];
  float* out = (float*)d_out;
  char* ws = (char*)d_ws;
  const size_t MB = 1024u*1024u;
  u16* xb  = (u16*)(ws + 0*MB);
  u16* wb  = (u16*)(ws + 8*MB);
  u16* wob = (u16*)(ws + 14*MB);
  u16* qb  = (u16*)(ws + 16*MB);
  u16* kb  = (u16*)(ws + 24*MB);
  u16* vtb = (u16*)(ws + 32*MB);
  u16* ob  = (u16*)(ws + 40*MB);
  float* attn_out = (float*)(ws + 48*MB);

  k_cast<<<2048, 256, 0, stream>>>(x, xb);
  k_cast_w<<<2048, 256, 0, stream>>>(Wq, Wk, Wv, Wo, wb, wob);
  k_gemm_nt<0><<<dim3(24,32), 256, 0, stream>>>(xb, wb, nullptr, qb, kb, vtb, 1024, 3072);
  k_attn<<<512, 512, 0, stream>>>(qb, kb, vtb, ob);
  k_gemm_nt<1><<<dim3(8,32), 256, 0, stream>>>(ob, wob, attn_out, nullptr, nullptr, nullptr, 1024, 1024);
  k_tail<<<1024, 256, 0, stream>>>(x, attn_out, g1, b1, Win, b_in, Wout, b_out, ry, g2, b2, out);
}

// Round 8
// 278.963 us; speedup vs baseline: 1.1767x; 1.1767x over previous
//
#include <hip/hip_runtime.h>
#include <stdint.h>

// _TransformerBlockQuantum on MI355X (gfx950).
// cast->bf16 | fused QKV GEMM (+V-transpose epilogue, XCD swizzle) | flash attn
// (wave-private double-buffered gload_lds staging, counted vmcnt waits, ZERO
// block barriers; 32x32 MFMA swapped ops, in-register P via permlane32_swap,
// log2 softmax, defer-max) | Wo GEMM | fused tail.

typedef unsigned short u16;
typedef unsigned int   u32;
typedef __bf16 bf16x8 __attribute__((ext_vector_type(8)));
typedef u16    u16x8  __attribute__((ext_vector_type(8)));
typedef u16    u16x4  __attribute__((ext_vector_type(4)));
typedef float  f32x4  __attribute__((ext_vector_type(4)));
typedef float  f32x16 __attribute__((ext_vector_type(16)));

#define DEV static __device__ __forceinline__

DEV u16 f2b(float f){ u32 u = __float_as_uint(f); return (u16)((u + 0x7fffu + ((u>>16)&1u)) >> 16); }
DEV u16 b2u(__bf16 h){ union{__bf16 b; u16 u;} c; c.b = h; return c.u; }
DEV float exp2fast(float x){ return __builtin_amdgcn_exp2f(x); }  // v_exp_f32 (2^x)

// permlane32_swap(a,b): out0 = (lane<32) ? a(own) : b(partner); out1 = (lane<32) ? a(partner) : b(own)
DEV void plswap(u32 a, u32 b, u32& o0, u32& o1, int hi){
#if __has_builtin(__builtin_amdgcn_permlane32_swap)
  auto s = __builtin_amdgcn_permlane32_swap(a, b, false, false);
  o0 = s[0]; o1 = s[1];
#else
  u32 xa = __shfl_xor(a, 32), xb = __shfl_xor(b, 32);
  o0 = hi ? xb : a;
  o1 = hi ? b  : xa;
#endif
}

#define MFMA16(a,b,c) __builtin_amdgcn_mfma_f32_16x16x32_bf16((a),(b),(c),0,0,0)
#define MFMA32(a,b,c) __builtin_amdgcn_mfma_f32_32x32x16_bf16((a),(b),(c),0,0,0)
#define GLD16(gp,lp) __builtin_amdgcn_global_load_lds( \
    (const __attribute__((address_space(1))) u32*)(const void*)(gp), \
    (__attribute__((address_space(3))) u32*)(void*)(lp), 16, 0, 0)

// ---------------- cast f32 -> bf16, 8 elems/thread ----------------
__global__ __launch_bounds__(256) void k_cast(const float* __restrict__ src, u16* __restrict__ dst){
  const int i = blockIdx.x*256 + threadIdx.x;
  const f32x4* s = (const f32x4*)src + (size_t)i*2;
  f32x4 a = s[0], b = s[1];
  u16x8 o;
  o[0]=f2b(a.x); o[1]=f2b(a.y); o[2]=f2b(a.z); o[3]=f2b(a.w);
  o[4]=f2b(b.x); o[5]=f2b(b.y); o[6]=f2b(b.z); o[7]=f2b(b.w);
  ((u16x8*)dst)[i] = o;
}

// all 4 weight matrices in one launch
__global__ __launch_bounds__(256) void k_cast_w(
    const float* __restrict__ Wq, const float* __restrict__ Wk,
    const float* __restrict__ Wv, const float* __restrict__ Wo,
    u16* __restrict__ wb, u16* __restrict__ wob){
  const int r = blockIdx.x >> 9, bi = blockIdx.x & 511;
  const float* src = (r==0)?Wq:((r==1)?Wk:((r==2)?Wv:Wo));
  u16* dst = (r<3) ? (wb + (size_t)r*1048576) : wob;
  const int i = bi*256 + threadIdx.x;
  const f32x4* s = (const f32x4*)src + (size_t)i*2;
  f32x4 a = s[0], b = s[1];
  u16x8 o;
  o[0]=f2b(a.x); o[1]=f2b(a.y); o[2]=f2b(a.z); o[3]=f2b(a.w);
  o[4]=f2b(b.x); o[5]=f2b(b.y); o[6]=f2b(b.z); o[7]=f2b(b.w);
  ((u16x8*)dst)[i] = o;
}

// ---------------- C = A * B^T  (A:[M,K] bf16, B:[N,K] bf16) ----------------
// XCD-aware bijective block swizzle (nwg % 8 == 0 for both launches).
// MODE 0: N=3072 fused QKV epilogue -> q(*0.125*log2e)/k row-major; V -> vt[(p*64+d)][s]
// MODE 1: f32 epilogue into Cf[M][N]
template<int MODE>
__global__ __launch_bounds__(256) void k_gemm_nt(
    const u16* __restrict__ A, const u16* __restrict__ B,
    float* __restrict__ Cf, u16* __restrict__ Qo, u16* __restrict__ Ko, u16* __restrict__ Vt,
    int K, int N)
{
  __shared__ __attribute__((aligned(16))) u16 As[128*64];
  __shared__ __attribute__((aligned(16))) u16 Bs[128*64];
  const int tid = threadIdx.x, lane = tid & 63, w = tid >> 6;
  const int wr = w >> 1, wc = w & 1;
  // XCD swizzle: chunk tile space per XCD
  const int nwg = gridDim.x * gridDim.y;
  int lin = blockIdx.y * gridDim.x + blockIdx.x;
  lin = (lin & 7) * (nwg >> 3) + (lin >> 3);
  const int n0 = (lin % gridDim.x) * 128;
  const int m0 = (lin / gridDim.x) * 128;
  const int l15 = lane & 15, lg = lane >> 4;
  f32x4 acc[4][4] = {};
  const int lr = lane >> 3, lc = (lane & 7)*8;
  const u16* ag = A + (size_t)(m0 + w*32 + lr)*K + lc;
  const u16* bg = B + (size_t)(n0 + w*32 + lr)*K + lc;
  u16* asl = &As[(w*32)*64];
  u16* bsl = &Bs[(w*32)*64];
  for (int k0 = 0; k0 < K; k0 += 64){
    __syncthreads();
    #pragma unroll
    for (int c = 0; c < 4; ++c){
      GLD16(ag + (size_t)(c*8)*K + k0, asl + c*512);
      GLD16(bg + (size_t)(c*8)*K + k0, bsl + c*512);
    }
    __syncthreads();
    #pragma unroll
    for (int kk = 0; kk < 2; ++kk){
      const int ko = kk*32 + lg*8;
      bf16x8 af[4], bf[4];
      #pragma unroll
      for (int t=0;t<4;++t) af[t] = *(const bf16x8*)&As[(wr*64 + t*16 + l15)*64 + ko];
      #pragma unroll
      for (int t=0;t<4;++t) bf[t] = *(const bf16x8*)&Bs[(wc*64 + t*16 + l15)*64 + ko];
      #pragma unroll
      for (int i=0;i<4;++i)
        #pragma unroll
        for (int j=0;j<4;++j)
          acc[i][j] = MFMA16(af[i], bf[j], acc[i][j]);
    }
  }
  const int col0 = n0 + wc*64 + l15;
  const int row0 = m0 + wr*64 + lg*4;
  if (MODE==0){
    const int which = n0 >> 10;   // uniform per block
    if (which == 2){
      #pragma unroll
      for (int i=0;i<4;++i){
        const int rr0 = row0 + i*16;
        const int bsel = rr0 >> 11, ss = rr0 & 2047;
        #pragma unroll
        for (int j=0;j<4;++j){
          const int d_loc = (col0 + j*16) & 1023;
          const int hh = d_loc >> 6, dd = d_loc & 63;
          u16x4 pk;
          #pragma unroll
          for (int r=0;r<4;++r) pk[r] = f2b(acc[i][j][r]);
          *(u16x4*)(Vt + ((size_t)((bsel*16 + hh)*64 + dd))*2048 + ss) = pk;
        }
      }
    } else {
      u16* dst = which ? Ko : Qo;
      const float scl = which ? 1.f : 0.125f*1.44269504f;  // fold log2(e) into q
      #pragma unroll
      for (int i=0;i<4;++i)
      #pragma unroll
      for (int j=0;j<4;++j){
        const int cc = (col0 + j*16) & 1023;
        #pragma unroll
        for (int r=0;r<4;++r)
          dst[(size_t)(row0 + i*16 + r)*1024 + cc] = f2b(acc[i][j][r]*scl);
      }
    }
  } else {
    #pragma unroll
    for (int i=0;i<4;++i)
    #pragma unroll
    for (int j=0;j<4;++j){
      const int cc = col0 + j*16;
      #pragma unroll
      for (int r=0;r<4;++r)
        Cf[(size_t)(row0 + i*16 + r)*N + cc] = acc[i][j][r];
    }
  }
}

// ---------------- flash attention: wave-private staging, no block barriers ----
// grid 512, 256 threads: blockIdx = p*16 + qt; p=(b*16+h). 4 waves x 32 q-rows.
// Each wave owns a 16KB LDS slot (2 bufs x [K 4KB | V 4KB]) and walks all 2048 kv
// in 64 tiles of 32, double-buffered via global_load_lds + counted s_waitcnt
// vmcnt(8) (wave-local -> no __syncthreads in the loop at all).
// K tile [32 rows][128B], swizzle (row&7)<<4 (pre-swizzled global source).
// V tile [64 d-rows][64B], swizzle (row&3)<<4.
// QK^T: S^T = MFMA32(Kfrag,Qfrag); PV: O^T = MFMA32(Vfrag,Pfrag); P in-register
// via cvt+permlane32_swap. q pre-scaled by 0.125*log2e; softmax in log2 domain.
__global__ __launch_bounds__(256, 2) void k_attn(
    const u16* __restrict__ q, const u16* __restrict__ k,
    const u16* __restrict__ vt, u16* __restrict__ o)
{
  __shared__ __attribute__((aligned(16))) char WS[65536];  // 4 waves x 16KB
  const int tid = threadIdx.x, lane = tid & 63, wl = tid >> 6;
  const int p = blockIdx.x >> 4, qt = blockIdx.x & 15;
  const int b = p >> 4, h = p & 15;
  const int l31 = lane & 31, hi = lane >> 5;
  const int qrow = b*2048 + qt*128 + wl*32 + l31;
  // Q fragments (B operand): col=q (lane l31), k-dim = d = kk*16 + hi*8 + j
  bf16x8 qa[4];
  #pragma unroll
  for (int kk=0;kk<4;++kk)
    qa[kk] = *(const bf16x8*)(q + (size_t)qrow*1024 + h*64 + kk*16 + hi*8);
  // pre-swizzled global staging sources (linear LDS dest = lane*16 within 1KB chunk)
  const char* kgl[4]; const char* vgl[4];
  #pragma unroll
  for (int c=0;c<4;++c){
    const int rowK = c*8 + (lane >> 3);
    const int cbK  = ((lane & 7)*16) ^ ((rowK & 7) << 4);
    kgl[c] = (const char*)k + ((size_t)(b*2048 + rowK))*2048 + h*128 + cbK;   // + it*65536
    const int rowV = c*16 + (lane >> 2);
    const int cbV  = ((lane & 3)*16) ^ ((rowV & 3) << 4);
    vgl[c] = (const char*)vt + ((size_t)(p*64 + rowV))*4096 + cbV;            // + it*64
  }
  char* wbase = WS + wl*16384;
  // prologue: stage tile 0 into buf 0
  #pragma unroll
  for (int c=0;c<4;++c){ GLD16(kgl[c], wbase + c*1024); GLD16(vgl[c], wbase + 4096 + c*1024); }
  f32x16 oacc[2] = {};
  float mrow = -1e30f, lrow = 0.f;
  const int kswz = (l31 & 7) << 4, vswz = (l31 & 3) << 4;
  for (int it = 0; it < 64; ++it){
    char* db = wbase + ((it & 1) << 13);
    if (it < 63){
      char* nb = wbase + (((it+1) & 1) << 13);
      const size_t ko = (size_t)(it+1)*65536;
      const int    vo = (it+1)*64;
      #pragma unroll
      for (int c=0;c<4;++c){ GLD16(kgl[c] + ko, nb + c*1024); GLD16(vgl[c] + vo, nb + 4096 + c*1024); }
      asm volatile("s_waitcnt vmcnt(8)" ::: "memory");   // current tile's 8 loads done
    } else {
      asm volatile("s_waitcnt vmcnt(0)" ::: "memory");
    }
    __builtin_amdgcn_sched_barrier(0);
    // QK^T: one 32x32 S^T tile, K=64 in 4 slices
    bf16x8 kf[4];
    #pragma unroll
    for (int kk=0;kk<4;++kk)
      kf[kk] = *(const bf16x8*)(db + l31*128 + ((kk*32 + hi*16) ^ kswz));
    f32x16 sacc = {};
    __builtin_amdgcn_s_setprio(1);
    #pragma unroll
    for (int kk=0;kk<4;++kk) sacc = MFMA32(kf[kk], qa[kk], sacc);
    __builtin_amdgcn_s_setprio(0);
    // V fragments (overlap with softmax below)
    bf16x8 vf[2][2];
    #pragma unroll
    for (int dt=0;dt<2;++dt)
      #pragma unroll
      for (int op=0;op<2;++op)
        vf[dt][op] = *(const bf16x8*)(db + 4096 + (dt*32 + l31)*64 + ((op*32 + hi*16) ^ vswz));
    // online softmax (log2 domain); partner lane^32 holds complementary kv slots
    float mx = sacc[0];
    #pragma unroll
    for (int i=1;i<16;++i) mx = fmaxf(mx, sacc[i]);
    mx = fmaxf(mx, __shfl_xor(mx, 32));
    if (!__all(mx <= mrow + 8.f)){       // defer-max
      const float mnew = fmaxf(mrow, mx);
      const float scl = exp2fast(mrow - mnew);
      mrow = mnew; lrow *= scl;
      #pragma unroll
      for (int dt=0;dt<2;++dt)
        #pragma unroll
        for (int i=0;i<16;++i) oacc[dt][i] *= scl;
    }
    float rsum = 0.f;
    #pragma unroll
    for (int i=0;i<16;++i){
      const float e = exp2fast(sacc[i] - mrow);
      sacc[i] = e; rsum += e;
    }
    rsum += __shfl_xor(rsum, 32);
    lrow += rsum;
    // pack P to bf16 pairs
    u32 pk[8];
    #pragma unroll
    for (int u=0;u<8;++u){
      const int idx = (u>>1)*4 + (u&1)*2;
      pk[u] = (u32)b2u((__bf16)sacc[idx]) | ((u32)b2u((__bf16)sacc[idx+1]) << 16);
    }
    // PV B-frags via permlane32_swap: lane needs P[q=l31][kv = op*16 + hi*8 + j]
    bf16x8 pb[2];
    #pragma unroll
    for (int op=0;op<2;++op){
      const int base = op*4;
      u32 w0,w1,w2,w3;
      plswap(pk[base+0], pk[base+2], w0, w2, hi);
      plswap(pk[base+1], pk[base+3], w1, w3, hi);
      union { u32 u[4]; bf16x8 v; } cc;
      cc.u[0]=w0; cc.u[1]=w1; cc.u[2]=w2; cc.u[3]=w3;
      pb[op] = cc.v;
    }
    // PV: O^T[d][q], two 32-d tiles, kv=32 in 2 slices
    __builtin_amdgcn_s_setprio(1);
    #pragma unroll
    for (int dt=0;dt<2;++dt)
      #pragma unroll
      for (int op=0;op<2;++op)
        oacc[dt] = MFMA32(vf[dt][op], pb[op], oacc[dt]);
    __builtin_amdgcn_s_setprio(0);
  }
  // epilogue: O[q][d] = O^T[d][q]/l
  const float rinv = 1.f / lrow;
  u16* orow = o + (size_t)qrow*1024 + h*64;
  #pragma unroll
  for (int dt=0;dt<2;++dt)
    #pragma unroll
    for (int rg=0;rg<4;++rg)
      #pragma unroll
      for (int hf=0;hf<2;++hf){
        const int r0 = rg*4 + hf*2;
        const u32 lo = b2u((__bf16)(oacc[dt][r0]   * rinv));
        const u32 hh = b2u((__bf16)(oacc[dt][r0+1] * rinv));
        *(u32*)(orow + dt*32 + rg*8 + hi*4 + hf*2) = lo | (hh << 16);
      }
}

// ---------------- fused tail: LN1(x+attn) -> quantum FFN -> +res -> LN2 ----------------
__global__ __launch_bounds__(256) void k_tail(
    const float* __restrict__ x, const float* __restrict__ attn,
    const float* __restrict__ g1, const float* __restrict__ b1,
    const float* __restrict__ Win, const float* __restrict__ b_in,
    const float* __restrict__ Wout, const float* __restrict__ b_out,
    const float* __restrict__ ry,
    const float* __restrict__ g2, const float* __restrict__ b2,
    float* __restrict__ out)
{
  const int tid = threadIdx.x, lane = tid & 63, w = tid >> 6;
  const int t = blockIdx.x*4 + w;
  const size_t base = (size_t)t*1024;
  f32x4 yv[4];
  float s1 = 0.f, s2 = 0.f;
  #pragma unroll
  for (int c=0;c<4;++c){
    const int idx = c*256 + lane*4;
    f32x4 xv = *(const f32x4*)(x + base + idx);
    f32x4 av = *(const f32x4*)(attn + base + idx);
    f32x4 y = xv + av;
    yv[c] = y;
    s1 += y.x + y.y + y.z + y.w;
    s2 += y.x*y.x + y.y*y.y + y.z*y.z + y.w*y.w;
  }
  #pragma unroll
  for (int off=32; off; off>>=1){ s1 += __shfl_xor(s1, off); s2 += __shfl_xor(s2, off); }
  {
    const float mu = s1*(1.f/1024.f);
    const float rinv = rsqrtf(s2*(1.f/1024.f) - mu*mu + 1e-5f);
    #pragma unroll
    for (int c=0;c<4;++c){
      const int idx = c*256 + lane*4;
      f32x4 gv = *(const f32x4*)(g1 + idx);
      f32x4 bv = *(const f32x4*)(b1 + idx);
      f32x4 y = yv[c];
      y.x = (y.x-mu)*rinv*gv.x + bv.x;
      y.y = (y.y-mu)*rinv*gv.y + bv.y;
      y.z = (y.z-mu)*rinv*gv.z + bv.z;
      y.w = (y.w-mu)*rinv*gv.w + bv.w;
      yv[c] = y;
    }
  }
  float ang[8];
  #pragma unroll
  for (int qq=0; qq<8; ++qq){
    float acc = 0.f;
    #pragma unroll
    for (int c=0;c<4;++c){
      f32x4 wv = *(const f32x4*)(Win + qq*1024 + c*256 + lane*4);
      acc += wv.x*yv[c].x + wv.y*yv[c].y + wv.z*yv[c].z + wv.w*yv[c].w;
    }
    ang[qq] = acc;
  }
  #pragma unroll
  for (int off=32; off; off>>=1)
    #pragma unroll
    for (int qq=0; qq<8; ++qq) ang[qq] += __shfl_xor(ang[qq], off);
  #pragma unroll
  for (int qq=0; qq<8; ++qq) ang[qq] += b_in[qq];
  float vr[4], vi[4];
  #pragma unroll
  for (int r=0;r<4;++r){ vr[r]=0.f; vi[r]=0.f; }
  if (lane==0) vr[0] = 1.f;
  #pragma unroll
  for (int wi=0; wi<8; ++wi){       // RX(ang)
    float s, c; __sincosf(ang[wi]*0.5f, &s, &c);
    const int pbit = 7 - wi;
    if (pbit >= 6){
      const int rp = 1 << (pbit-6);
      #pragma unroll
      for (int r=0;r<4;++r) if (!(r & rp)){
        const int r2 = r | rp;
        float ar=vr[r], ai=vi[r], br=vr[r2], bi=vi[r2];
        vr[r]  = c*ar + s*bi;  vi[r]  = c*ai - s*br;
        vr[r2] = c*br + s*ai;  vi[r2] = c*bi - s*ar;
      }
    } else {
      const int msk = 1 << pbit;
      #pragma unroll
      for (int r=0;r<4;++r){
        float orr = __shfl_xor(vr[r], msk);
        float oii = __shfl_xor(vi[r], msk);
        float nr = c*vr[r] + s*oii;
        float ni = c*vi[r] - s*orr;
        vr[r]=nr; vi[r]=ni;
      }
    }
  }
  #pragma unroll
  for (int wi=0; wi<8; ++wi){       // RY(ry)
    float s, c; __sincosf(ry[wi]*0.5f, &s, &c);
    const int pbit = 7 - wi;
    if (pbit >= 6){
      const int rp = 1 << (pbit-6);
      #pragma unroll
      for (int r=0;r<4;++r) if (!(r & rp)){
        const int r2 = r | rp;
        float ar=vr[r], ai=vi[r], br=vr[r2], bi=vi[r2];
        vr[r]  = c*ar - s*br;  vi[r]  = c*ai - s*bi;
        vr[r2] = s*ar + c*br;  vi[r2] = s*ai + c*bi;
      }
    } else {
      const int msk = 1 << pbit;
      const float sg = (lane & msk) ? s : -s;
      #pragma unroll
      for (int r=0;r<4;++r){
        float orr = __shfl_xor(vr[r], msk);
        float oii = __shfl_xor(vi[r], msk);
        float nr = c*vr[r] + sg*orr;
        float ni = c*vi[r] + sg*oii;
        vr[r]=nr; vi[r]=ni;
      }
    }
  }
  { float tr=vr[2]; vr[2]=vr[3]; vr[3]=tr; float ti=vi[2]; vi[2]=vi[3]; vi[3]=ti; }
  vr[1]=__shfl_xor(vr[1],32); vi[1]=__shfl_xor(vi[1],32);
  vr[3]=__shfl_xor(vr[3],32); vi[3]=__shfl_xor(vi[3],32);
  #pragma unroll
  for (int cn=2; cn<7; ++cn){
    const int pc = 7-cn, pt = pc-1;
    const bool ctl = (lane >> pc) & 1;
    #pragma unroll
    for (int r=0;r<4;++r){
      float tr = __shfl_xor(vr[r], 1<<pt);
      float ti = __shfl_xor(vi[r], 1<<pt);
      if (ctl){ vr[r]=tr; vi[r]=ti; }
    }
  }
  float pr[4];
  #pragma unroll
  for (int r=0;r<4;++r) pr[r] = vr[r]*vr[r] + vi[r]*vi[r];
  float e[8];
  e[0] = (pr[0]+pr[1]) - (pr[2]+pr[3]);
  e[1] = (pr[0]+pr[2]) - (pr[1]+pr[3]);
  const float tot = pr[0]+pr[1]+pr[2]+pr[3];
  #pragma unroll
  for (int wi=2; wi<8; ++wi){
    const int pbit = 7-wi;
    e[wi] = ((lane >> pbit) & 1) ? -tot : tot;
  }
  #pragma unroll
  for (int off=1; off<64; off<<=1)
    #pragma unroll
    for (int i=0;i<8;++i) e[i] += __shfl_xor(e[i], off);
  float yy[4][4];
  s1 = 0.f; s2 = 0.f;
  #pragma unroll
  for (int c=0;c<4;++c){
    const float x1a[4] = {yv[c].x, yv[c].y, yv[c].z, yv[c].w};
    #pragma unroll
    for (int j=0;j<4;++j){
      const int d = c*256 + lane*4 + j;
      f32x4 w0 = *(const f32x4*)(Wout + (size_t)d*8);
      f32x4 w1 = *(const f32x4*)(Wout + (size_t)d*8 + 4);
      float acc = b_out[d];
      acc += w0.x*e[0] + w0.y*e[1] + w0.z*e[2] + w0.w*e[3];
      acc += w1.x*e[4] + w1.y*e[5] + w1.z*e[6] + w1.w*e[7];
      const float y = x1a[j] + fmaxf(acc, 0.f);
      yy[c][j] = y;
      s1 += y; s2 += y*y;
    }
  }
  #pragma unroll
  for (int off=32; off; off>>=1){ s1 += __shfl_xor(s1, off); s2 += __shfl_xor(s2, off); }
  const float mu = s1*(1.f/1024.f);
  const float rinv = rsqrtf(s2*(1.f/1024.f) - mu*mu + 1e-5f);
  #pragma unroll
  for (int c=0;c<4;++c){
    const int idx = c*256 + lane*4;
    f32x4 gv = *(const f32x4*)(g2 + idx);
    f32x4 bv = *(const f32x4*)(b2 + idx);
    f32x4 ov;
    ov.x = (yy[c][0]-mu)*rinv*gv.x + bv.x;
    ov.y = (yy[c][1]-mu)*rinv*gv.y + bv.y;
    ov.z = (yy[c][2]-mu)*rinv*gv.z + bv.z;
    ov.w = (yy[c][3]-mu)*rinv*gv.w + bv.w;
    *(f32x4*)(out + base + idx) = ov;
  }
}

extern "C" void kernel_launch(void* const* d_in, const int* in_sizes, int n_in,
                              void* d_out, int out_size, void* d_ws, size_t ws_size,
                              hipStream_t stream)
{
  const float* x    = (const float*)d_in[0];
  const float* Wq   = (const float*)d_in[1];
  const float* Wk   = (const float*)d_in[2];
  const float* Wv   = (const float*)d_in[3];
  const float* Wo   = (const float*)d_in[4];
  const float* g1   = (const float*)d_in[5];
  const float* b1   = (const float*)d_in[6];
  const float* g2   = (const float*)d_in[7];
  const float* b2   = (const float*)d_in[8];
  const float* Win  = (const float*)d_in[9];
  const float* b_in = (const float*)d_in[10];
  const float* Wout = (const float*)d_in[11];
  const float* b_out= (const float*)d_in[12];
  const float* ry   = (const float*)d_in[13];
  float* out = (float*)d_out;
  char* ws = (char*)d_ws;
  const size_t MB = 1024u*1024u;
  u16* xb  = (u16*)(ws + 0*MB);
  u16* wb  = (u16*)(ws + 8*MB);
  u16* wob = (u16*)(ws + 14*MB);
  u16* qb  = (u16*)(ws + 16*MB);
  u16* kb  = (u16*)(ws + 24*MB);
  u16* vtb = (u16*)(ws + 32*MB);
  u16* ob  = (u16*)(ws + 40*MB);
  float* attn_out = (float*)(ws + 48*MB);

  k_cast<<<2048, 256, 0, stream>>>(x, xb);
  k_cast_w<<<2048, 256, 0, stream>>>(Wq, Wk, Wv, Wo, wb, wob);
  k_gemm_nt<0><<<dim3(24,32), 256, 0, stream>>>(xb, wb, nullptr, qb, kb, vtb, 1024, 3072);
  k_attn<<<512, 256, 0, stream>>>(qb, kb, vtb, ob);
  k_gemm_nt<1><<<dim3(8,32), 256, 0, stream>>>(ob, wob, attn_out, nullptr, nullptr, nullptr, 1024, 1024);
  k_tail<<<1024, 256, 0, stream>>>(x, attn_out, g1, b1, Win, b_in, Wout, b_out, ry, g2, b2, out);
}